// Round 1
// baseline (378.405 us; speedup 1.0000x reference)
//
#include <hip/hip_runtime.h>
#include <hip/hip_fp16.h>

#define N_NODES   50000
#define N_EDGES   800000
#define D         64
#define N_CLASSES 10
#define N_GRAPHS  128
#define ELLW      48   // max in-degree bound: Poisson(16), P(any deg>=48) ~ 1e-6; input fixed
#define CPAD      16   // counters padded to one per 64B line (atomic line-serialization fix)

// ELL entry is PACKED 4B: low16 = src node id (<50000<65536), high16 = ew as fp16.
// Rationale: scatter writebacks are per-(line,XCD) partial flushes; 8B->4B slots
// halve the dirtied-line footprint (WRITE_SIZE was 64B/edge = 51.2MB).

__device__ __forceinline__ float unpack_ew(int p) {
    return __half2float(__ushort_as_half((unsigned short)((unsigned)p >> 16)));
}

// ---------------- fused setup: edge scatter + layer-1 GEMM ----------------
// Scatter is scattered-write-bound with VALUBusy~0.5%; gemm1 (x@W1) is pure VALU
// and independent -> co-schedule in one dispatch, interleaved every 4th block.
__global__ __launch_bounds__(256) void scatter_gemm(const int* __restrict__ src,
                                                    const int* __restrict__ dst,
                                                    const float* __restrict__ ew,
                                                    int* __restrict__ count,
                                                    unsigned int* __restrict__ ell,
                                                    const float* __restrict__ x,
                                                    const float* __restrict__ W1,
                                                    __half* __restrict__ xwh) {
    __shared__ float Wl[D * D];  // 16KB; scatter blocks don't use it (not occupancy-limiting)
    const int bid = blockIdx.x;

    if ((bid & 3) != 3) {
        // ---- scatter path: 3126 blocks, one edge per thread ----
        int sb = bid - (bid >> 2);            // scatter ordinal 0..3125
        int e = sb * 256 + threadIdx.x;
        if (e < N_EDGES) {
            int s = src[e], d = dst[e];
            float w = ew[e];
            int c = atomicAdd(&count[d * CPAD], 1);
            if (c < ELLW) {
                unsigned int p = (unsigned int)s |
                                 ((unsigned int)__half_as_ushort(__float2half_rn(w)) << 16);
                ell[d * ELLW + c] = p;
            }
        }
    } else {
        // ---- gemm path: 1041 blocks (bid>>2 = 0..1040), lane holds W[:,lane] ----
        for (int i = threadIdx.x; i < D * D; i += blockDim.x) Wl[i] = W1[i];
        __syncthreads();  // block-uniform branch: safe

        const int lane = threadIdx.x & 63;
        float w[D];
#pragma unroll
        for (int k = 0; k < D; ++k) w[k] = Wl[k * D + lane];

        const int gw = (bid >> 2) * 4 + (threadIdx.x >> 6);
        const int nw = 1041 * 4;
        const int chunk = (N_NODES + nw - 1) / nw;  // 13
        int r0 = __builtin_amdgcn_readfirstlane(gw * chunk);
        int r1 = min(r0 + chunk, N_NODES);

        for (int row = r0; row < r1; ++row) {
            const float4* xr = (const float4*)(x + (size_t)row * D);  // uniform ptr
            float acc = 0.0f;
#pragma unroll
            for (int k4 = 0; k4 < D / 4; ++k4) {
                float4 xv = xr[k4];
                acc = fmaf(xv.x, w[4 * k4 + 0], acc);
                acc = fmaf(xv.y, w[4 * k4 + 1], acc);
                acc = fmaf(xv.z, w[4 * k4 + 2], acc);
                acc = fmaf(xv.w, w[4 * k4 + 3], acc);
            }
            xwh[(size_t)row * D + lane] = __float2half(acc);
        }
    }
}

// Wave per node: deg = 1 + sum(ew over slots), dinv = rsqrt(deg). Atomic-free.
__global__ __launch_bounds__(256) void node_dinv(const int* __restrict__ count,
                                                 const unsigned int* __restrict__ ell,
                                                 float* __restrict__ dinv) {
    const int lane = threadIdx.x & 63;
    const int gwave = (blockIdx.x * blockDim.x + threadIdx.x) >> 6;
    const int nw = (gridDim.x * blockDim.x) >> 6;
    for (int i = gwave; i < N_NODES; i += nw) {
        int cnt = min(count[i * CPAD], ELLW);
        float w = (lane < cnt) ? unpack_ew((int)ell[i * ELLW + lane]) : 0.0f;
#pragma unroll
        for (int off = 32; off >= 1; off >>= 1) w += __shfl_xor(w, off);
        if (lane == 0) dinv[i] = rsqrtf(1.0f + w);
    }
}

// ---------------- per-layer kernels ----------------

// xw_fp16 = in @ W (layers 2,3). Same body as the fused gemm path.
__global__ __launch_bounds__(256) void gemm_rows(const float* __restrict__ in,
                                                 const float* __restrict__ W,
                                                 __half* __restrict__ xwh) {
    __shared__ float Wl[D * D];
    for (int i = threadIdx.x; i < D * D; i += blockDim.x) Wl[i] = W[i];
    __syncthreads();

    const int lane = threadIdx.x & 63;
    float w[D];
#pragma unroll
    for (int k = 0; k < D; ++k) w[k] = Wl[k * D + lane];  // 2-way bank alias: free

    const int gwave = (blockIdx.x * blockDim.x + threadIdx.x) >> 6;
    const int nw = (gridDim.x * blockDim.x) >> 6;
    const int chunk = (N_NODES + nw - 1) / nw;
    int r0 = __builtin_amdgcn_readfirstlane(gwave * chunk);
    int r1 = min(r0 + chunk, N_NODES);

    for (int row = r0; row < r1; ++row) {
        const float4* xr = (const float4*)(in + (size_t)row * D);
        float acc = 0.0f;
#pragma unroll
        for (int k4 = 0; k4 < D / 4; ++k4) {
            float4 xv = xr[k4];
            acc = fmaf(xv.x, w[4 * k4 + 0], acc);
            acc = fmaf(xv.y, w[4 * k4 + 1], acc);
            acc = fmaf(xv.z, w[4 * k4 + 2], acc);
            acc = fmaf(xv.w, w[4 * k4 + 3], acc);
        }
        xwh[(size_t)row * D + lane] = __float2half(acc);
    }
}

// agg[i] = f( dv*(dv*xw[i] + sum_j dinv[src_j]*ew_j*xw[src_j]) + bias ).
// ell_norm pass eliminated: dinv[src] is a wave-uniform scalar load (readfirstlane
// -> s_load, own lgkm counter, overlaps the fp16 row gathers on vmcnt).
// Packed meta: int4 = 4 edges / 16B uniform load (was 2); rows 16B-aligned (192B).
__global__ __launch_bounds__(256) void node_agg(const int* __restrict__ count,
                                                const unsigned int* __restrict__ ell,
                                                const float* __restrict__ dinv,
                                                const __half* __restrict__ xwh,
                                                const float* __restrict__ bias,
                                                float* __restrict__ agg,
                                                int relu) {
    const int lane = threadIdx.x & 63;
    const int gwave = (blockIdx.x * blockDim.x + threadIdx.x) >> 6;
    const int nw = (gridDim.x * blockDim.x) >> 6;
    const float bv = bias[lane];

    for (int row = gwave; row < N_NODES; row += nw) {
        int cnt = min(count[row * CPAD], ELLW);
        float dv = dinv[row];
        const int4* m4 = (const int4*)(ell + (size_t)row * ELLW);
        // out = dv^2*self + dv*sum(ds*ew*v) + b  ->  acc = dv*self + sum((ds*ew)*v); r = acc*dv + b
        float acc = __half2float(xwh[(size_t)row * D + lane]) * dv;
        int j = 0;
        for (; j + 8 <= cnt; j += 8) {
            int4 a = m4[j / 4 + 0];  // edges j..j+3 (uniform -> broadcast)
            int4 b = m4[j / 4 + 1];  // edges j+4..j+7
            int p0 = __builtin_amdgcn_readfirstlane(a.x);
            int p1 = __builtin_amdgcn_readfirstlane(a.y);
            int p2 = __builtin_amdgcn_readfirstlane(a.z);
            int p3 = __builtin_amdgcn_readfirstlane(a.w);
            int p4 = __builtin_amdgcn_readfirstlane(b.x);
            int p5 = __builtin_amdgcn_readfirstlane(b.y);
            int p6 = __builtin_amdgcn_readfirstlane(b.z);
            int p7 = __builtin_amdgcn_readfirstlane(b.w);
            float v0 = __half2float(xwh[(size_t)(p0 & 0xFFFF) * D + lane]);
            float v1 = __half2float(xwh[(size_t)(p1 & 0xFFFF) * D + lane]);
            float v2 = __half2float(xwh[(size_t)(p2 & 0xFFFF) * D + lane]);
            float v3 = __half2float(xwh[(size_t)(p3 & 0xFFFF) * D + lane]);
            float v4 = __half2float(xwh[(size_t)(p4 & 0xFFFF) * D + lane]);
            float v5 = __half2float(xwh[(size_t)(p5 & 0xFFFF) * D + lane]);
            float v6 = __half2float(xwh[(size_t)(p6 & 0xFFFF) * D + lane]);
            float v7 = __half2float(xwh[(size_t)(p7 & 0xFFFF) * D + lane]);
            float d0 = dinv[p0 & 0xFFFF], d1 = dinv[p1 & 0xFFFF];
            float d2 = dinv[p2 & 0xFFFF], d3 = dinv[p3 & 0xFFFF];
            float d4 = dinv[p4 & 0xFFFF], d5 = dinv[p5 & 0xFFFF];
            float d6 = dinv[p6 & 0xFFFF], d7 = dinv[p7 & 0xFFFF];
            acc = fmaf(v0, d0 * unpack_ew(p0), acc);
            acc = fmaf(v1, d1 * unpack_ew(p1), acc);
            acc = fmaf(v2, d2 * unpack_ew(p2), acc);
            acc = fmaf(v3, d3 * unpack_ew(p3), acc);
            acc = fmaf(v4, d4 * unpack_ew(p4), acc);
            acc = fmaf(v5, d5 * unpack_ew(p5), acc);
            acc = fmaf(v6, d6 * unpack_ew(p6), acc);
            acc = fmaf(v7, d7 * unpack_ew(p7), acc);
        }
        for (; j + 4 <= cnt; j += 4) {
            int4 a = m4[j / 4];
            int p0 = __builtin_amdgcn_readfirstlane(a.x);
            int p1 = __builtin_amdgcn_readfirstlane(a.y);
            int p2 = __builtin_amdgcn_readfirstlane(a.z);
            int p3 = __builtin_amdgcn_readfirstlane(a.w);
            float v0 = __half2float(xwh[(size_t)(p0 & 0xFFFF) * D + lane]);
            float v1 = __half2float(xwh[(size_t)(p1 & 0xFFFF) * D + lane]);
            float v2 = __half2float(xwh[(size_t)(p2 & 0xFFFF) * D + lane]);
            float v3 = __half2float(xwh[(size_t)(p3 & 0xFFFF) * D + lane]);
            float d0 = dinv[p0 & 0xFFFF], d1 = dinv[p1 & 0xFFFF];
            float d2 = dinv[p2 & 0xFFFF], d3 = dinv[p3 & 0xFFFF];
            acc = fmaf(v0, d0 * unpack_ew(p0), acc);
            acc = fmaf(v1, d1 * unpack_ew(p1), acc);
            acc = fmaf(v2, d2 * unpack_ew(p2), acc);
            acc = fmaf(v3, d3 * unpack_ew(p3), acc);
        }
        for (; j < cnt; ++j) {
            int p = __builtin_amdgcn_readfirstlane((int)ell[(size_t)row * ELLW + j]);
            float v = __half2float(xwh[(size_t)(p & 0xFFFF) * D + lane]);
            acc = fmaf(v, dinv[p & 0xFFFF] * unpack_ew(p), acc);
        }
        float r = fmaf(acc, dv, bv);
        agg[(size_t)row * D + lane] = relu ? fmaxf(r, 0.0f) : r;
    }
}

// ---------------- pooling + classifier ----------------

__global__ __launch_bounds__(256) void pool(const float* __restrict__ agg3,
                                            const int* __restrict__ batch,
                                            float* __restrict__ pooled,
                                            float* __restrict__ cnt) {
    const int lane = threadIdx.x & 63;
    const int gwave = (blockIdx.x * blockDim.x + threadIdx.x) >> 6;
    const int nw = (gridDim.x * blockDim.x) >> 6;
    const int chunk = (N_NODES + nw - 1) / nw;
    int r0 = gwave * chunk;
    int r1 = min(r0 + chunk, N_NODES);
    if (r0 >= r1) return;

    int g = batch[r0];
    float acc = 0.0f;
    int c = 0;
    for (int row = r0; row < r1; ++row) {
        int gg = batch[row];
        if (gg != g) {
            atomicAdd(&pooled[g * D + lane], acc);
            if (lane == 0) atomicAdd(&cnt[g], (float)c);
            g = gg; acc = 0.0f; c = 0;
        }
        acc += agg3[(size_t)row * D + lane];
        ++c;
    }
    atomicAdd(&pooled[g * D + lane], acc);
    if (lane == 0) atomicAdd(&cnt[g], (float)c);
}

__global__ __launch_bounds__(64) void final_lin(const float* __restrict__ pooled,
                                                const float* __restrict__ cnt,
                                                const float* __restrict__ Wlin,
                                                const float* __restrict__ blin,
                                                float* __restrict__ out) {
    __shared__ float row[D];
    int g = blockIdx.x;
    int t = threadIdx.x;
    float c = fmaxf(cnt[g], 1.0f);
    row[t] = pooled[g * D + t] / c;
    __syncthreads();
    if (t < N_CLASSES) {
        float acc = blin[t];
#pragma unroll
        for (int k = 0; k < D; ++k) acc = fmaf(row[k], Wlin[k * N_CLASSES + t], acc);
        out[g * N_CLASSES + t] = acc;
    }
}

// ---------------- launch ----------------

extern "C" void kernel_launch(void* const* d_in, const int* in_sizes, int n_in,
                              void* d_out, int out_size, void* d_ws, size_t ws_size,
                              hipStream_t stream) {
    const float* x     = (const float*)d_in[0];
    const int*   ei    = (const int*)d_in[1];
    const int*   src   = ei;
    const int*   dst   = ei + N_EDGES;
    const int*   batch = (const int*)d_in[2];
    const float* ew    = (const float*)d_in[3];
    const float* W1    = (const float*)d_in[4];
    const float* b1    = (const float*)d_in[5];
    const float* W2    = (const float*)d_in[6];
    const float* b2    = (const float*)d_in[7];
    const float* W3    = (const float*)d_in[8];
    const float* b3    = (const float*)d_in[9];
    const float* Wlin  = (const float*)d_in[10];
    const float* blin  = (const float*)d_in[11];
    float* out = (float*)d_out;

    // workspace layout (4B units)
    float*        ws     = (float*)d_ws;
    __half*       xwh    = (__half*)ws;                    // 50000*64 half = 1,600,000 floats
    float*        agg    = ws + 1600000;                   // 3,200,000
    unsigned int* ell    = (unsigned int*)(ws + 4800000);  // 50000*48 u32 = 2,400,000 floats
    float*        dinv   = ws + 7200000;                   // 50,000
    int*          count  = (int*)(ws + 7250000);           // 50000*16 = 800,000 (line-padded)
    float*        pooled = ws + 8050000;                   // 8,192
    float*        cnt    = ws + 8058192;                   // 128
    // total ~8.06M * 4B = ~32.2 MB

    const int B = 256;

    hipMemsetAsync(count, 0, N_NODES * CPAD * sizeof(int), stream);
    hipMemsetAsync(pooled, 0, (N_GRAPHS * D + N_GRAPHS) * sizeof(float), stream);

    const int aggBlocks = 3125;  // 12500 waves, 4 nodes each

    // fused: ELL build (3126 blocks) + layer-1 gemm (1041 blocks), interleaved bid&3
    scatter_gemm<<<4167, B, 0, stream>>>(src, dst, ew, count, ell, x, W1, xwh);
    node_dinv<<<aggBlocks, B, 0, stream>>>(count, ell, dinv);

    // layer 1: h1 = relu(agg(x@W1) + b1)   (norm folded into agg)
    node_agg<<<aggBlocks, B, 0, stream>>>(count, ell, dinv, xwh, b1, agg, 1);
    // layer 2
    gemm_rows<<<1024, B, 0, stream>>>(agg, W2, xwh);
    node_agg<<<aggBlocks, B, 0, stream>>>(count, ell, dinv, xwh, b2, agg, 1);
    // layer 3 (no relu)
    gemm_rows<<<1024, B, 0, stream>>>(agg, W3, xwh);
    node_agg<<<aggBlocks, B, 0, stream>>>(count, ell, dinv, xwh, b3, agg, 0);

    // global mean pool and classifier
    pool<<<196, B, 0, stream>>>(agg, batch, pooled, cnt);
    final_lin<<<N_GRAPHS, 64, 0, stream>>>(pooled, cnt, Wlin, blin, out);
}

// Round 2
// 336.888 us; speedup vs baseline: 1.1232x; 1.1232x over previous
//
#include <hip/hip_runtime.h>
#include <hip/hip_fp16.h>

#define N_NODES   50000
#define N_EDGES   800000
#define D         64
#define N_CLASSES 10
#define N_GRAPHS  128
#define ELLW      48   // max in-degree bound: Poisson(16), P(any deg>=48) ~ 1e-6; input fixed
#define CPAD      16   // counters padded to one per 64B line (atomic line-serialization fix)
#define NXCD      8
#define DPART     (N_NODES / NXCD)   // 6250 dst nodes per XCD partition

// ELL entry is PACKED 4B: low16 = src node id (<50000<65536), high16 = ew as fp16.
// (4B packing alone did NOT cut WRITE_SIZE -- the amplification is cross-XCD
// line sharing; fixed by the partitioned scatter below. Packing still halves
// downstream ELL meta reads, so it stays.)

__device__ __forceinline__ float unpack_ew(int p) {
    return __half2float(__ushort_as_half((unsigned short)((unsigned)p >> 16)));
}

// ---------------- setup kernels ----------------

// XCD-partitioned scatter: block-group g = bid%8 (dispatch round-robins groups
// across XCDs) owns dst range [g*6250, (g+1)*6250). Each group scans ALL edges
// and keeps its own: every ELL/count line is then written by exactly ONE XCD's
// L2 (group footprint ~1.6MB << 4MB L2), accumulates, and writes back once.
// Edge reads are 8x-amplified but near-simultaneous across groups -> L3-served.
// Correctness never depends on the bid->XCD mapping; only locality does.
__global__ __launch_bounds__(256) void ell_scatter(const int* __restrict__ src,
                                                   const int* __restrict__ dst,
                                                   const float* __restrict__ ew,
                                                   int* __restrict__ count,
                                                   unsigned int* __restrict__ ell) {
    const int grp = blockIdx.x & (NXCD - 1);
    const int ord = blockIdx.x >> 3;          // 0..390
    const int lo  = grp * DPART;
#pragma unroll
    for (int i = 0; i < 8; ++i) {
        int e = ord * 2048 + i * 256 + threadIdx.x;
        if (e < N_EDGES) {
            int d = dst[e];
            if ((unsigned)(d - lo) < (unsigned)DPART) {
                int s = src[e];
                float w = ew[e];
                int c = atomicAdd(&count[d * CPAD], 1);
                if (c < ELLW) {
                    ell[d * ELLW + c] = (unsigned int)s |
                        ((unsigned int)__half_as_ushort(__float2half_rn(w)) << 16);
                }
            }
        }
    }
}

// Wave per node: deg = 1 + sum(ew over slots), dinv = rsqrt(deg). Atomic-free.
__global__ __launch_bounds__(256) void node_dinv(const int* __restrict__ count,
                                                 const unsigned int* __restrict__ ell,
                                                 float* __restrict__ dinv) {
    const int lane = threadIdx.x & 63;
    const int gwave = (blockIdx.x * blockDim.x + threadIdx.x) >> 6;
    const int nw = (gridDim.x * blockDim.x) >> 6;
    for (int i = gwave; i < N_NODES; i += nw) {
        int cnt = min(count[i * CPAD], ELLW);
        float w = (lane < cnt) ? unpack_ew((int)ell[i * ELLW + lane]) : 0.0f;
#pragma unroll
        for (int off = 32; off >= 1; off >>= 1) w += __shfl_xor(w, off);
        if (lane == 0) dinv[i] = rsqrtf(1.0f + w);
    }
}

// ---------------- per-layer kernels ----------------

// xw_fp16 = in @ W. Shuffle-free: lane holds W[:,lane] in 64 VGPRs; x-row loads
// are wave-uniform (readfirstlane'd range) -> scalar broadcasts; inner loop is
// pure v_fmac. Bias/relu fused into node_agg epilogue instead.
// NOTE: kept as its OWN dispatch -- round-1 fusion with the scatter charged its
// 104 VGPRs to the latency-bound scatter blocks (occupancy 52%->9%, -2x).
__global__ __launch_bounds__(256) void gemm_rows(const float* __restrict__ in,
                                                 const float* __restrict__ W,
                                                 __half* __restrict__ xwh) {
    __shared__ float Wl[D * D];
    for (int i = threadIdx.x; i < D * D; i += blockDim.x) Wl[i] = W[i];
    __syncthreads();

    const int lane = threadIdx.x & 63;
    float w[D];
#pragma unroll
    for (int k = 0; k < D; ++k) w[k] = Wl[k * D + lane];  // 2-way bank alias: free

    const int gwave = (blockIdx.x * blockDim.x + threadIdx.x) >> 6;
    const int nw = (gridDim.x * blockDim.x) >> 6;
    const int chunk = (N_NODES + nw - 1) / nw;
    int r0 = __builtin_amdgcn_readfirstlane(gwave * chunk);
    int r1 = min(r0 + chunk, N_NODES);

    for (int row = r0; row < r1; ++row) {
        const float4* xr = (const float4*)(in + (size_t)row * D);  // uniform ptr
        float acc = 0.0f;
#pragma unroll
        for (int k4 = 0; k4 < D / 4; ++k4) {
            float4 xv = xr[k4];  // s_load_dwordx4 (uniform)
            acc = fmaf(xv.x, w[4 * k4 + 0], acc);
            acc = fmaf(xv.y, w[4 * k4 + 1], acc);
            acc = fmaf(xv.z, w[4 * k4 + 2], acc);
            acc = fmaf(xv.w, w[4 * k4 + 3], acc);
        }
        xwh[(size_t)row * D + lane] = __float2half(acc);
    }
}

// agg[i] = f( dv*(dv*xw[i] + sum_j dinv[src_j]*ew_j*xw[src_j]) + bias ).
// ell_norm pass eliminated: dinv[src] is a wave-uniform scalar load (readfirstlane
// -> s_load, own lgkm counter, overlaps the fp16 row gathers on vmcnt).
// Packed meta: int4 = 4 edges / 16B uniform load; rows 16B-aligned (192B).
__global__ __launch_bounds__(256) void node_agg(const int* __restrict__ count,
                                                const unsigned int* __restrict__ ell,
                                                const float* __restrict__ dinv,
                                                const __half* __restrict__ xwh,
                                                const float* __restrict__ bias,
                                                float* __restrict__ agg,
                                                int relu) {
    const int lane = threadIdx.x & 63;
    const int gwave = (blockIdx.x * blockDim.x + threadIdx.x) >> 6;
    const int nw = (gridDim.x * blockDim.x) >> 6;
    const float bv = bias[lane];

    for (int row = gwave; row < N_NODES; row += nw) {
        int cnt = min(count[row * CPAD], ELLW);
        float dv = dinv[row];
        const int4* m4 = (const int4*)(ell + (size_t)row * ELLW);
        // out = dv^2*self + dv*sum(ds*ew*v) + b  ->  acc = dv*self + sum((ds*ew)*v); r = acc*dv + b
        float acc = __half2float(xwh[(size_t)row * D + lane]) * dv;
        int j = 0;
        for (; j + 8 <= cnt; j += 8) {
            int4 a = m4[j / 4 + 0];  // edges j..j+3 (uniform -> broadcast)
            int4 b = m4[j / 4 + 1];  // edges j+4..j+7
            int p0 = __builtin_amdgcn_readfirstlane(a.x);
            int p1 = __builtin_amdgcn_readfirstlane(a.y);
            int p2 = __builtin_amdgcn_readfirstlane(a.z);
            int p3 = __builtin_amdgcn_readfirstlane(a.w);
            int p4 = __builtin_amdgcn_readfirstlane(b.x);
            int p5 = __builtin_amdgcn_readfirstlane(b.y);
            int p6 = __builtin_amdgcn_readfirstlane(b.z);
            int p7 = __builtin_amdgcn_readfirstlane(b.w);
            float v0 = __half2float(xwh[(size_t)(p0 & 0xFFFF) * D + lane]);
            float v1 = __half2float(xwh[(size_t)(p1 & 0xFFFF) * D + lane]);
            float v2 = __half2float(xwh[(size_t)(p2 & 0xFFFF) * D + lane]);
            float v3 = __half2float(xwh[(size_t)(p3 & 0xFFFF) * D + lane]);
            float v4 = __half2float(xwh[(size_t)(p4 & 0xFFFF) * D + lane]);
            float v5 = __half2float(xwh[(size_t)(p5 & 0xFFFF) * D + lane]);
            float v6 = __half2float(xwh[(size_t)(p6 & 0xFFFF) * D + lane]);
            float v7 = __half2float(xwh[(size_t)(p7 & 0xFFFF) * D + lane]);
            float d0 = dinv[p0 & 0xFFFF], d1 = dinv[p1 & 0xFFFF];
            float d2 = dinv[p2 & 0xFFFF], d3 = dinv[p3 & 0xFFFF];
            float d4 = dinv[p4 & 0xFFFF], d5 = dinv[p5 & 0xFFFF];
            float d6 = dinv[p6 & 0xFFFF], d7 = dinv[p7 & 0xFFFF];
            acc = fmaf(v0, d0 * unpack_ew(p0), acc);
            acc = fmaf(v1, d1 * unpack_ew(p1), acc);
            acc = fmaf(v2, d2 * unpack_ew(p2), acc);
            acc = fmaf(v3, d3 * unpack_ew(p3), acc);
            acc = fmaf(v4, d4 * unpack_ew(p4), acc);
            acc = fmaf(v5, d5 * unpack_ew(p5), acc);
            acc = fmaf(v6, d6 * unpack_ew(p6), acc);
            acc = fmaf(v7, d7 * unpack_ew(p7), acc);
        }
        for (; j + 4 <= cnt; j += 4) {
            int4 a = m4[j / 4];
            int p0 = __builtin_amdgcn_readfirstlane(a.x);
            int p1 = __builtin_amdgcn_readfirstlane(a.y);
            int p2 = __builtin_amdgcn_readfirstlane(a.z);
            int p3 = __builtin_amdgcn_readfirstlane(a.w);
            float v0 = __half2float(xwh[(size_t)(p0 & 0xFFFF) * D + lane]);
            float v1 = __half2float(xwh[(size_t)(p1 & 0xFFFF) * D + lane]);
            float v2 = __half2float(xwh[(size_t)(p2 & 0xFFFF) * D + lane]);
            float v3 = __half2float(xwh[(size_t)(p3 & 0xFFFF) * D + lane]);
            float d0 = dinv[p0 & 0xFFFF], d1 = dinv[p1 & 0xFFFF];
            float d2 = dinv[p2 & 0xFFFF], d3 = dinv[p3 & 0xFFFF];
            acc = fmaf(v0, d0 * unpack_ew(p0), acc);
            acc = fmaf(v1, d1 * unpack_ew(p1), acc);
            acc = fmaf(v2, d2 * unpack_ew(p2), acc);
            acc = fmaf(v3, d3 * unpack_ew(p3), acc);
        }
        for (; j < cnt; ++j) {
            int p = __builtin_amdgcn_readfirstlane((int)ell[(size_t)row * ELLW + j]);
            float v = __half2float(xwh[(size_t)(p & 0xFFFF) * D + lane]);
            acc = fmaf(v, dinv[p & 0xFFFF] * unpack_ew(p), acc);
        }
        float r = fmaf(acc, dv, bv);
        agg[(size_t)row * D + lane] = relu ? fmaxf(r, 0.0f) : r;
    }
}

// ---------------- pooling + classifier ----------------

// batch sorted: contiguous chunk per wave, register accumulate, flush per boundary.
__global__ __launch_bounds__(256) void pool(const float* __restrict__ agg3,
                                            const int* __restrict__ batch,
                                            float* __restrict__ pooled,
                                            float* __restrict__ cnt) {
    const int lane = threadIdx.x & 63;
    const int gwave = (blockIdx.x * blockDim.x + threadIdx.x) >> 6;
    const int nw = (gridDim.x * blockDim.x) >> 6;
    const int chunk = (N_NODES + nw - 1) / nw;
    int r0 = gwave * chunk;
    int r1 = min(r0 + chunk, N_NODES);
    if (r0 >= r1) return;

    int g = batch[r0];
    float acc = 0.0f;
    int c = 0;
    for (int row = r0; row < r1; ++row) {
        int gg = batch[row];
        if (gg != g) {
            atomicAdd(&pooled[g * D + lane], acc);
            if (lane == 0) atomicAdd(&cnt[g], (float)c);
            g = gg; acc = 0.0f; c = 0;
        }
        acc += agg3[(size_t)row * D + lane];
        ++c;
    }
    atomicAdd(&pooled[g * D + lane], acc);
    if (lane == 0) atomicAdd(&cnt[g], (float)c);
}

__global__ __launch_bounds__(64) void final_lin(const float* __restrict__ pooled,
                                                const float* __restrict__ cnt,
                                                const float* __restrict__ Wlin,
                                                const float* __restrict__ blin,
                                                float* __restrict__ out) {
    __shared__ float row[D];
    int g = blockIdx.x;
    int t = threadIdx.x;
    float c = fmaxf(cnt[g], 1.0f);
    row[t] = pooled[g * D + t] / c;
    __syncthreads();
    if (t < N_CLASSES) {
        float acc = blin[t];
#pragma unroll
        for (int k = 0; k < D; ++k) acc = fmaf(row[k], Wlin[k * N_CLASSES + t], acc);
        out[g * N_CLASSES + t] = acc;
    }
}

// ---------------- launch ----------------

extern "C" void kernel_launch(void* const* d_in, const int* in_sizes, int n_in,
                              void* d_out, int out_size, void* d_ws, size_t ws_size,
                              hipStream_t stream) {
    const float* x     = (const float*)d_in[0];
    const int*   ei    = (const int*)d_in[1];
    const int*   src   = ei;
    const int*   dst   = ei + N_EDGES;
    const int*   batch = (const int*)d_in[2];
    const float* ew    = (const float*)d_in[3];
    const float* W1    = (const float*)d_in[4];
    const float* b1    = (const float*)d_in[5];
    const float* W2    = (const float*)d_in[6];
    const float* b2    = (const float*)d_in[7];
    const float* W3    = (const float*)d_in[8];
    const float* b3    = (const float*)d_in[9];
    const float* Wlin  = (const float*)d_in[10];
    const float* blin  = (const float*)d_in[11];
    float* out = (float*)d_out;

    // workspace layout (4B units)
    float*        ws     = (float*)d_ws;
    __half*       xwh    = (__half*)ws;                    // 50000*64 half = 1,600,000 floats
    float*        agg    = ws + 1600000;                   // 3,200,000
    unsigned int* ell    = (unsigned int*)(ws + 4800000);  // 50000*48 u32 = 2,400,000 floats
    float*        dinv   = ws + 7200000;                   // 50,000
    int*          count  = (int*)(ws + 7250000);           // 50000*16 = 800,000 (line-padded)
    float*        pooled = ws + 8050000;                   // 8,192
    float*        cnt    = ws + 8058192;                   // 128
    // total ~8.06M * 4B = ~32.2 MB

    const int B = 256;

    hipMemsetAsync(count, 0, N_NODES * CPAD * sizeof(int), stream);
    hipMemsetAsync(pooled, 0, (N_GRAPHS * D + N_GRAPHS) * sizeof(float), stream);

    const int aggBlocks = 3125;  // 12500 waves, 4 nodes each

    // ELL build: 8 groups x 391 blocks; group = bid&7 owns one dst partition.
    ell_scatter<<<391 * NXCD, B, 0, stream>>>(src, dst, ew, count, ell);
    node_dinv<<<aggBlocks, B, 0, stream>>>(count, ell, dinv);

    // layer 1: h1 = relu(agg(x@W1) + b1)   (norm folded into agg)
    gemm_rows<<<1024, B, 0, stream>>>(x, W1, xwh);
    node_agg<<<aggBlocks, B, 0, stream>>>(count, ell, dinv, xwh, b1, agg, 1);
    // layer 2
    gemm_rows<<<1024, B, 0, stream>>>(agg, W2, xwh);
    node_agg<<<aggBlocks, B, 0, stream>>>(count, ell, dinv, xwh, b2, agg, 1);
    // layer 3 (no relu)
    gemm_rows<<<1024, B, 0, stream>>>(agg, W3, xwh);
    node_agg<<<aggBlocks, B, 0, stream>>>(count, ell, dinv, xwh, b3, agg, 0);

    // global mean pool and classifier
    pool<<<196, B, 0, stream>>>(agg, batch, pooled, cnt);
    final_lin<<<N_GRAPHS, 64, 0, stream>>>(pooled, cnt, Wlin, blin, out);
}